// Round 2
// 112.408 us; speedup vs baseline: 1.0344x; 1.0344x over previous
//
#include <hip/hip_runtime.h>
#include <hip/hip_bf16.h>

typedef __bf16 bf16x8 __attribute__((ext_vector_type(8)));
typedef unsigned short u16x8 __attribute__((ext_vector_type(8)));
typedef unsigned int u32x2 __attribute__((ext_vector_type(2)));
typedef unsigned int u32x4 __attribute__((ext_vector_type(4)));
typedef float f32x4 __attribute__((ext_vector_type(4)));
typedef unsigned short u16;

constexpr int DIMc = 256, Tt = 2048, Dd = 64;

__device__ __forceinline__ u16 f2b(float f) {   // RNE float->bf16 bits
  unsigned u = __float_as_uint(f);
  return (u16)((u + 0x7FFFu + ((u >> 16) & 1u)) >> 16);
}
__device__ __forceinline__ float b2f(u16 v) {
  return __uint_as_float(((unsigned)v) << 16);
}
__device__ __forceinline__ unsigned f2b2(float a, float b) {  // packed RNE pair (low=a)
  return (unsigned)f2b(a) | ((unsigned)f2b(b) << 16);
}
__device__ __forceinline__ f32x4 mfma16(u16x8 a, u16x8 b, f32x4 c) {
  return __builtin_amdgcn_mfma_f32_16x16x32_bf16(
      __builtin_bit_cast(bf16x8, a), __builtin_bit_cast(bf16x8, b), c, 0, 0, 0);
}

// One fused kernel: no prep pass, no workspace. Weights (Win/Wout/cb, 384 KB total)
// are L2/LLC-resident across all 256 blocks; each block converts its own bf16 copies.
// Block = 128 tokens, 512 threads (8 waves). Wave w owns tokens [w*16, w*16+16).
// LDS (u16 offsets): WinT[64][288] @0 ; InT[128][256] @18432 (WoX[256][72] aliased
// here after encode) ; Xt[128][64] @51200 ; Xm[128][64] (-2x) @59392 ; mnp @67584.
// Total 139,264 B. 3 barriers total.
__global__ __launch_bounds__(512, 2) void nsvq_fused(
    const float* __restrict__ in, const float* __restrict__ rnd,
    const float* __restrict__ cb, const float* __restrict__ Win,
    const float* __restrict__ bin, const float* __restrict__ Wout,
    const float* __restrict__ bout, float* __restrict__ out) {
  __shared__ u16 sm[69632];
  u16* const WinT = sm;                     // [64][288] bf16 (stride 288: banks balanced)
  u16* const InT  = sm + 18432;             // [128][256] bf16, 16B-block XOR swizzle
  u16* const WoX  = sm + 18432;             // [256][72] bf16 (aliases InT after encode)
  u16* const Xt   = sm + 51200;             // [128][64] bf16 x, swizzled
  u16* const Xm   = sm + 59392;             // [128][64] bf16 -2x, swizzled
  float* const mnp = (float*)(sm + 67584);  // [8][128] per-wave code-slice mins

  const int tid  = threadIdx.x;
  const int lane = tid & 63;
  const int w    = tid >> 6;                // 0..7
  const int quad = lane >> 4, col = lane & 15;
  const int b    = blockIdx.x >> 4;         // 256 blocks
  const int t0   = (blockIdx.x & 15) << 7;
  const int myt  = w * 16 + col;            // own token row in block

  // ---- stage WinT: Win[c][d] -> WinT[d][c] bf16 (lanes = consecutive c => conflict-free writes) ----
  {
    const int c = tid & 255, db = tid >> 8;
    #pragma unroll
    for (int k = 0; k < 4; ++k) {
      const int d0 = db * 32 + k * 8;
      const float4* wr = (const float4*)(Win + c * 64 + d0);
      float4 v0 = wr[0], v1 = wr[1];
      u16* dst = WinT + c;
      dst[(d0 + 0) * 288] = f2b(v0.x); dst[(d0 + 1) * 288] = f2b(v0.y);
      dst[(d0 + 2) * 288] = f2b(v0.z); dst[(d0 + 3) * 288] = f2b(v0.w);
      dst[(d0 + 4) * 288] = f2b(v1.x); dst[(d0 + 5) * 288] = f2b(v1.y);
      dst[(d0 + 6) * 288] = f2b(v1.z); dst[(d0 + 7) * 288] = f2b(v1.w);
    }
  }
  // ---- stage InT (fp32 -> bf16, transpose, packed 16B writes) ----
  {
    const int t = tid & 127, cg = tid >> 7;
    const float* ib = in + (size_t)b * DIMc * Tt + t0 + t;
    #pragma unroll
    for (int it = 0; it < 8; ++it) {
      const int c0 = cg * 8 + it * 32;
      u32x4 pk;
      #pragma unroll
      for (int jj = 0; jj < 4; ++jj)
        pk[jj] = f2b2(ib[(size_t)(c0 + 2 * jj) * Tt], ib[(size_t)(c0 + 2 * jj + 1) * Tt]);
      *(u32x4*)(InT + t * 256 + (((c0 >> 3) ^ (t & 7)) << 3)) = pk;
    }
  }
  // ---- rr2 of own token (full-wave reduce, keep via lane select) ----
  float rr2v = 0.f;
  const float* rb = rnd + ((size_t)b * Tt + t0) * Dd;
  #pragma unroll
  for (int tt = 0; tt < 16; ++tt) {
    float v = rb[(size_t)(w * 16 + tt) * Dd + lane];
    float s = v * v;
    s += __shfl_xor(s, 1);  s += __shfl_xor(s, 2);  s += __shfl_xor(s, 4);
    s += __shfl_xor(s, 8);  s += __shfl_xor(s, 16); s += __shfl_xor(s, 32);
    if (col == tt) rr2v = s;
  }
  __syncthreads();   // InT + WinT ready

  // ---- encode: X^T = WinT · InT, acc init = bin (f32-exact bias) ----
  f32x4 acc[4];
  {
    u16x8 Bf[8];
    #pragma unroll
    for (int kt = 0; kt < 8; ++kt)
      Bf[kt] = *(const u16x8*)(InT + myt * 256 + (((kt * 4 + quad) ^ (myt & 7)) << 3));
    #pragma unroll
    for (int mt = 0; mt < 4; ++mt) {
      float4 bi = *(const float4*)(bin + mt * 16 + quad * 4);
      f32x4 a = {bi.x, bi.y, bi.z, bi.w};
      #pragma unroll
      for (int kt = 0; kt < 8; ++kt) {
        u16x8 A = *(const u16x8*)(WinT + (mt * 16 + col) * 288 + kt * 32 + quad * 8);
        a = mfma16(A, Bf[kt], a);
      }
      acc[mt] = a;
    }
  }
  float x2v = 0.f;
  #pragma unroll
  for (int mt = 0; mt < 4; ++mt) {
    #pragma unroll
    for (int r = 0; r < 4; ++r) x2v = fmaf(acc[mt][r], acc[mt][r], x2v);
    u32x2 px = { f2b2(acc[mt][0], acc[mt][1]), f2b2(acc[mt][2], acc[mt][3]) };
    // bf16(-2x) == -2*bf16(x) exactly -> distance products bit-match the old scheme
    u32x2 pm = { f2b2(-2.f * acc[mt][0], -2.f * acc[mt][1]),
                 f2b2(-2.f * acc[mt][2], -2.f * acc[mt][3]) };
    const int bk  = mt * 2 + (quad >> 1);
    const int off = myt * 64 + ((bk ^ (myt & 7)) << 3) + (quad & 1) * 4;
    *(u32x2*)(Xt + off) = px;
    *(u32x2*)(Xm + off) = pm;
  }
  x2v += __shfl_xor(x2v, 16);
  x2v += __shfl_xor(x2v, 32);
  __syncthreads();   // Xt/Xm complete; InT dead -> WoX can alias

  // ---- stage WoX: Wout[d][c] -> WoX[c][d] (coalesced reads, b128 conflict-free writes) ----
  {
    const int c = tid & 255, db = tid >> 8;
    #pragma unroll
    for (int k = 0; k < 4; ++k) {
      const int d0 = db * 32 + k * 8;
      u32x4 pk;
      #pragma unroll
      for (int jj = 0; jj < 4; ++jj)
        pk[jj] = f2b2(Wout[(size_t)(d0 + 2 * jj) * 256 + c],
                      Wout[(size_t)(d0 + 2 * jj + 1) * 256 + c]);
      *(u32x4*)(WoX + c * 72 + d0) = pk;
    }
  }
  // ---- distances: wave-private 128-code slice, cb global->regs (no LDS round-trip);
  //      acc init = c^2 (f32-exact, replaces the norm MFMA) ----
  u16x8 Xa[8], Xb[8];
  #pragma unroll
  for (int nt = 0; nt < 8; ++nt) {
    const int tr = nt * 16 + col;
    Xa[nt] = *(const u16x8*)(Xm + tr * 64 + ((quad ^ (tr & 7)) << 3));
    Xb[nt] = *(const u16x8*)(Xm + tr * 64 + (((4 + quad) ^ (tr & 7)) << 3));
  }
  float minv[8];
  #pragma unroll
  for (int i = 0; i < 8; ++i) minv[i] = 3.4e38f;
  const float* cw = cb + (size_t)(w * 128) * Dd;
  for (int mi = 0; mi < 8; ++mi) {
    const float* cr = cw + (size_t)(mi * 16 + col) * Dd + quad * 8;
    float4 c0 = ((const float4*)cr)[0],        c1 = ((const float4*)cr)[1];
    float4 c2 = ((const float4*)(cr + 32))[0], c3 = ((const float4*)(cr + 32))[1];
    float cnA = fmaf(c0.w, c0.w, fmaf(c0.z, c0.z, fmaf(c0.y, c0.y, c0.x * c0.x)));
    float cnB = fmaf(c1.w, c1.w, fmaf(c1.z, c1.z, fmaf(c1.y, c1.y, c1.x * c1.x)));
    float cnC = fmaf(c2.w, c2.w, fmaf(c2.z, c2.z, fmaf(c2.y, c2.y, c2.x * c2.x)));
    float cnD = fmaf(c3.w, c3.w, fmaf(c3.z, c3.z, fmaf(c3.y, c3.y, c3.x * c3.x)));
    float cn = (cnA + cnB) + (cnC + cnD);
    cn += __shfl_xor(cn, 16); cn += __shfl_xor(cn, 32);   // sum quads -> full ||c||^2
    f32x4 cn4;
    #pragma unroll
    for (int r = 0; r < 4; ++r) cn4[r] = __shfl(cn, quad * 4 + r);
    u32x4 a0 = { f2b2(c0.x, c0.y), f2b2(c0.z, c0.w), f2b2(c1.x, c1.y), f2b2(c1.z, c1.w) };
    u32x4 a1 = { f2b2(c2.x, c2.y), f2b2(c2.z, c2.w), f2b2(c3.x, c3.y), f2b2(c3.z, c3.w) };
    u16x8 A0 = __builtin_bit_cast(u16x8, a0);
    u16x8 A1 = __builtin_bit_cast(u16x8, a1);
    #pragma unroll
    for (int nt = 0; nt < 8; ++nt) {
      f32x4 a = mfma16(A0, Xa[nt], cn4);    // c^2 + (-2x)·c
      a = mfma16(A1, Xb[nt], a);
      #pragma unroll
      for (int r = 0; r < 4; ++r) minv[nt] = fminf(minv[nt], a[r]);
    }
  }
  #pragma unroll
  for (int nt = 0; nt < 8; ++nt) {
    float m = minv[nt];
    m = fminf(m, __shfl_xor(m, 16));
    m = fminf(m, __shfl_xor(m, 32));
    mnp[w * 128 + nt * 16 + col] = m;       // all quads write same value
  }
  __syncthreads();   // mnp + WoX ready

  // ---- q = x + sc*rnd (own token rows; lane = d) ----
  float mv = 3.4e38f;
  #pragma unroll
  for (int j = 0; j < 8; ++j) mv = fminf(mv, mnp[j * 128 + myt]);
  float r2  = fmaxf(x2v + mv, 0.f);                 // ||x - hard||^2
  float scv = sqrtf(r2) / (sqrtf(rr2v) + 1e-12f);
  #pragma unroll
  for (int tt = 0; tt < 16; ++tt) {
    float s  = __shfl(scv, tt);
    float rv = rb[(size_t)(w * 16 + tt) * Dd + lane];
    const int tr  = w * 16 + tt;
    const int idx = tr * 64 + (((lane >> 3) ^ (tr & 7)) << 3) + (lane & 7);
    Xt[idx] = f2b(fmaf(s, rv, b2f(Xt[idx])));
  }

  // ---- decode: out = WoX · q, acc init = bout (f32-exact bias) ----
  u16x8 Q0 = *(const u16x8*)(Xt + myt * 64 + ((quad ^ (myt & 7)) << 3));
  u16x8 Q1 = *(const u16x8*)(Xt + myt * 64 + (((4 + quad) ^ (myt & 7)) << 3));
  float* ob0 = out + (size_t)b * DIMc * Tt + t0 + myt;
  #pragma unroll
  for (int mt = 0; mt < 16; ++mt) {
    const u16* ar = WoX + (mt * 16 + col) * 72;
    u16x8 A0 = *(const u16x8*)(ar + quad * 8);
    u16x8 A1 = *(const u16x8*)(ar + 32 + quad * 8);
    float4 bo = *(const float4*)(bout + mt * 16 + quad * 4);
    f32x4 a = {bo.x, bo.y, bo.z, bo.w};
    a = mfma16(A0, Q0, a);
    a = mfma16(A1, Q1, a);
    float* ob = ob0 + (size_t)(mt * 16 + quad * 4) * Tt;
    #pragma unroll
    for (int r = 0; r < 4; ++r) ob[(size_t)r * Tt] = a[r];
  }
}

extern "C" void kernel_launch(void* const* d_in, const int* in_sizes, int n_in,
                              void* d_out, int out_size, void* d_ws, size_t ws_size,
                              hipStream_t stream) {
  const float *in = nullptr, *cbp = nullptr, *rnd = nullptr, *bin = nullptr, *bout = nullptr;
  const float* w16[2] = {nullptr, nullptr}; int nw = 0;
  for (int i = 0; i < n_in; ++i) {
    switch (in_sizes[i]) {
      case 8388608: in  = (const float*)d_in[i]; break;
      case 65536:   cbp = (const float*)d_in[i]; break;
      case 2097152: rnd = (const float*)d_in[i]; break;
      case 64:      bin = (const float*)d_in[i]; break;
      case 256:     bout= (const float*)d_in[i]; break;
      case 16384:   if (nw < 2) w16[nw++] = (const float*)d_in[i]; break;
      default: break;
    }
  }
  if (!in)   in  = (const float*)d_in[0];
  if (!cbp)  cbp = (const float*)d_in[1];
  if (nw < 2) { w16[0] = (const float*)d_in[2]; w16[1] = (const float*)d_in[4]; }
  if (!bin)  bin = (const float*)d_in[3];
  if (!bout) bout = (const float*)d_in[5];
  if (!rnd)  rnd = (const float*)d_in[6];

  nsvq_fused<<<256, 512, 0, stream>>>(in, rnd, cbp, w16[0], bin, w16[1], bout, (float*)d_out);
}